// Round 2
// baseline (487.055 us; speedup 1.0000x reference)
//
#include <hip/hip_runtime.h>

#define BB 4
#define CC 5
#define HH 200
#define DKk 20
#define DI 400
#define NPOS (BB*CC*HH)   // 4000

// ---------------------------------------------------------------------------
// Kernel 1: projections (all fp32). R6 redesign.
//   q/k/v[pos,d] = sum_n X[pos,n,d]*W[n] + b   (N=400, row = 20 floats = 80B)
//   c[pos,d]     = sum_n cdd[pos,n,d]*W1[n]+b1 (N=20)
// One WAVE per (tensor,pos). Lane l owns rows n = l, l+64, ... and loads each
// row CONTIGUOUSLY (5 float4 = 80B). A wave's 5-instr row-group covers a
// contiguous 5120B span -> zero overfetch, L1 line reuse. 15 independent
// loads in flight per lane (3-row batches) -> depth is structural, not
// compiler-dependent (R5 lesson: compiler collapsed x[16] to VGPR=32,
// depth~2, 1.6 TB/s). acc[20] has compile-time indices only. Butterfly
// shfl_xor reduce; lane 0 writes the 80B output row.
// Grid: 4*4000 waves = 4000 blocks x 256. No LDS, no syncthreads.
// ---------------------------------------------------------------------------
__global__ __launch_bounds__(256, 1) void proj_kernel(
    const float* __restrict__ Q,
    const float* __restrict__ K,
    const float* __restrict__ V,
    const float* __restrict__ cdd,
    const float* __restrict__ W,
    const float* __restrict__ bptr,
    const float* __restrict__ W1,
    const float* __restrict__ b1ptr,
    float* __restrict__ proj)   // [4][NPOS][20] : q,k,v,c
{
    const int wave = threadIdx.x >> 6;
    const int lane = threadIdx.x & 63;
    const int wid  = blockIdx.x * 4 + wave;   // 0..15999, exact
    const int tensor = wid / NPOS;            // 0..3 (wave-uniform)
    const int pos    = wid % NPOS;

    float acc[DKk];
    #pragma unroll
    for (int d = 0; d < DKk; ++d) acc[d] = 0.f;

    if (tensor < 3) {
        const float* base = (tensor == 0) ? Q : (tensor == 1) ? K : V;
        const float4* src = reinterpret_cast<const float4*>(
            base + (size_t)pos * (DI * DKk));

        // per-lane weights: coalesced 256B reads of the 1.6KB W (L1-resident)
        float w[6];
        #pragma unroll
        for (int i = 0; i < 6; ++i) w[i] = W[lane + 64 * i];

        // 2 batches of 3 rows: 15 independent float4 loads in flight each
        #pragma unroll
        for (int half = 0; half < 2; ++half) {
            float4 x[3][5];
            #pragma unroll
            for (int r = 0; r < 3; ++r) {
                const int n = lane + 64 * (half * 3 + r);   // <= 383 < 400
                #pragma unroll
                for (int q = 0; q < 5; ++q)
                    x[r][q] = src[n * 5 + q];
            }
            #pragma unroll
            for (int r = 0; r < 3; ++r) {
                const float wn = w[half * 3 + r];
                #pragma unroll
                for (int q = 0; q < 5; ++q) {
                    acc[4*q+0] += wn * x[r][q].x;
                    acc[4*q+1] += wn * x[r][q].y;
                    acc[4*q+2] += wn * x[r][q].z;
                    acc[4*q+3] += wn * x[r][q].w;
                }
            }
        }
        // tail: rows 384..399 (lanes 0..15)
        if (lane < DI - 6 * 64) {
            const int n = lane + 6 * 64;
            const float wn = W[n];
            float4 x[5];
            #pragma unroll
            for (int q = 0; q < 5; ++q) x[q] = src[n * 5 + q];
            #pragma unroll
            for (int q = 0; q < 5; ++q) {
                acc[4*q+0] += wn * x[q].x;
                acc[4*q+1] += wn * x[q].y;
                acc[4*q+2] += wn * x[q].z;
                acc[4*q+3] += wn * x[q].w;
            }
        }
    } else {
        // cdd: 20 rows of 80B; lanes 0..19 take one row each
        const float4* src = reinterpret_cast<const float4*>(
            cdd + (size_t)pos * (DKk * DKk));
        if (lane < DKk) {
            const float wn = W1[lane];
            float4 x[5];
            #pragma unroll
            for (int q = 0; q < 5; ++q) x[q] = src[lane * 5 + q];
            #pragma unroll
            for (int q = 0; q < 5; ++q) {
                acc[4*q+0] += wn * x[q].x;
                acc[4*q+1] += wn * x[q].y;
                acc[4*q+2] += wn * x[q].z;
                acc[4*q+3] += wn * x[q].w;
            }
        }
    }

    // full-wave butterfly: every lane ends with the complete sums
    #pragma unroll
    for (int m = 32; m >= 1; m >>= 1) {
        #pragma unroll
        for (int d = 0; d < DKk; ++d)
            acc[d] += __shfl_xor(acc[d], m);
    }

    if (lane == 0) {
        const float bias = (tensor < 3) ? bptr[0] : b1ptr[0];
        float4* dst = reinterpret_cast<float4*>(
            proj + ((size_t)tensor * NPOS + pos) * DKk);
        #pragma unroll
        for (int q = 0; q < 5; ++q) {
            float4 o;
            o.x = acc[4*q+0] + bias;
            o.y = acc[4*q+1] + bias;
            o.z = acc[4*q+2] + bias;
            o.w = acc[4*q+3] + bias;
            dst[q] = o;
        }
    }
}

// ---------------------------------------------------------------------------
// Kernel 2: attention WITH fused normalization. Per (b,c):
//   scores[h,g] = (q[h].k[g] + k[h].c[g])/sqrt(20); s = exp(scores)
// s values stay in registers (7/thread); rowsum via shfl_xor butterfly gives
// every lane the sum, so normalized attn is written directly.
// Grid: 20 bc * 25 row-tiles = 500 blocks; 256 thr = 8 rows * 32 subs.
// (Unchanged from R5 — passed; revisit only after its counters are visible.)
// ---------------------------------------------------------------------------
__global__ __launch_bounds__(256) void attn_kernel(
    const float* __restrict__ proj,
    float* __restrict__ attn_out,  // [NPOS][200] fp32, normalized (in d_out)
    float* __restrict__ ctx_out)   // [NPOS][20] fp32 (d_out head)
{
    __shared__ float sk[HH * DKk];
    __shared__ float sc[HH * DKk];
    __shared__ float sv[HH * DKk];

    int bc   = blockIdx.x / 25;
    int tile = blockIdx.x % 25;
    int t    = threadIdx.x;

    const float* kp = proj + ((size_t)1 * NPOS + bc * HH) * DKk;
    const float* vp = proj + ((size_t)2 * NPOS + bc * HH) * DKk;
    const float* cp = proj + ((size_t)3 * NPOS + bc * HH) * DKk;

    for (int i = t; i < HH * DKk / 4; i += 256) {
        reinterpret_cast<float4*>(sk)[i] = reinterpret_cast<const float4*>(kp)[i];
        reinterpret_cast<float4*>(sc)[i] = reinterpret_cast<const float4*>(cp)[i];
        reinterpret_cast<float4*>(sv)[i] = reinterpret_cast<const float4*>(vp)[i];
    }
    __syncthreads();

    int row = t >> 5;            // 0..7
    int sub = t & 31;            // 0..31
    int h   = tile * 8 + row;    // 0..199
    int rowIdx = bc * HH + h;

    const float* qr_p = proj + ((size_t)0 * NPOS + rowIdx) * DKk;
    const float* kr_p = proj + ((size_t)1 * NPOS + rowIdx) * DKk;
    float qr[DKk], kr[DKk];
    #pragma unroll
    for (int i = 0; i < 5; ++i) {
        float4 a = reinterpret_cast<const float4*>(qr_p)[i];
        qr[4*i] = a.x; qr[4*i+1] = a.y; qr[4*i+2] = a.z; qr[4*i+3] = a.w;
        float4 b = reinterpret_cast<const float4*>(kr_p)[i];
        kr[4*i] = b.x; kr[4*i+1] = b.y; kr[4*i+2] = b.z; kr[4*i+3] = b.w;
    }

    const float inv_sqrt = 0.22360679774997896f;  // 1/sqrt(20)
    float ctx[DKk];
    #pragma unroll
    for (int d = 0; d < DKk; ++d) ctx[d] = 0.f;
    float rs = 0.f;
    float sreg[7];   // s values kept in registers (static indexing via unroll)

    #pragma unroll
    for (int kk = 0; kk < 7; ++kk) {
        int g = sub + 32 * kk;
        float s = 0.f;
        if (g < HH) {
            float dot = 0.f;
            #pragma unroll
            for (int i = 0; i < 5; ++i) {
                float4 kg = reinterpret_cast<const float4*>(sk + g * DKk)[i];
                float4 cg = reinterpret_cast<const float4*>(sc + g * DKk)[i];
                dot += qr[4*i]   * kg.x + qr[4*i+1] * kg.y
                     + qr[4*i+2] * kg.z + qr[4*i+3] * kg.w;
                dot += kr[4*i]   * cg.x + kr[4*i+1] * cg.y
                     + kr[4*i+2] * cg.z + kr[4*i+3] * cg.w;
            }
            s = __expf(dot * inv_sqrt);
            #pragma unroll
            for (int i = 0; i < 5; ++i) {
                float4 vg = reinterpret_cast<const float4*>(sv + g * DKk)[i];
                ctx[4*i]   += s * vg.x;
                ctx[4*i+1] += s * vg.y;
                ctx[4*i+2] += s * vg.z;
                ctx[4*i+3] += s * vg.w;
            }
        }
        sreg[kk] = s;
        rs += s;
    }

    // rowsum: butterfly so ALL 32 lanes of the row hold the total
    #pragma unroll
    for (int off = 16; off >= 1; off >>= 1)
        rs += __shfl_xor(rs, off, 32);
    float inv = 1.0f / (rs + 1e-8f);

    // context reduce to sub==0
    #pragma unroll
    for (int off = 16; off >= 1; off >>= 1) {
        #pragma unroll
        for (int d = 0; d < DKk; ++d)
            ctx[d] += __shfl_down(ctx[d], (unsigned)off, 32);
    }

    if (sub == 0) {
        float* co = ctx_out + (size_t)rowIdx * DKk;
        #pragma unroll
        for (int i = 0; i < 5; ++i) {
            float4 o;
            o.x = ctx[4*i]   * inv;
            o.y = ctx[4*i+1] * inv;
            o.z = ctx[4*i+2] * inv;
            o.w = ctx[4*i+3] * inv;
            reinterpret_cast<float4*>(co)[i] = o;
        }
    }

    // normalized attn straight from registers (coalesced per 32-lane group)
    #pragma unroll
    for (int kk = 0; kk < 7; ++kk) {
        int g = sub + 32 * kk;
        if (g < HH)
            attn_out[(size_t)rowIdx * HH + g] = sreg[kk] * inv;
    }
}

extern "C" void kernel_launch(void* const* d_in, const int* in_sizes, int n_in,
                              void* d_out, int out_size, void* d_ws, size_t ws_size,
                              hipStream_t stream) {
    const float* Q   = (const float*)d_in[0];
    const float* K   = (const float*)d_in[1];
    const float* V   = (const float*)d_in[2];
    const float* cdd = (const float*)d_in[3];
    const float* W   = (const float*)d_in[4];
    const float* b   = (const float*)d_in[5];
    const float* W1  = (const float*)d_in[6];
    const float* b1  = (const float*)d_in[7];
    // d_in[8] = d_k (int) — compile-time constant 20

    float* proj = (float*)d_ws;           // 4*4000*20 = 320000 floats = 1.28 MB

    float* out      = (float*)d_out;
    float* ctx_out  = out;                // 80000 fp32 (context)
    float* attn_out = out + 80000;        // 800000 fp32 (attn)

    // one wave per (tensor,pos): 16000 waves = exactly 4000 blocks of 256
    proj_kernel<<<4000, 256, 0, stream>>>(
        Q, K, V, cdd, W, b, W1, b1, proj);
    attn_kernel<<<CC * BB * 25, 256, 0, stream>>>(proj, attn_out, ctx_out);
}

// Round 3
// 376.031 us; speedup vs baseline: 1.2953x; 1.2953x over previous
//
#include <hip/hip_runtime.h>

#define BB 4
#define CC 5
#define HH 200
#define DKk 20
#define DI 400
#define NPOS (BB*CC*HH)   // 4000

// ---------------------------------------------------------------------------
// Kernel 1: projections (all fp32). R7 redesign: PER-INSTRUCTION coalescing.
// R6 lesson: lane-stride-80B loads touch ~40 sectors/instr -> L1 thrash ->
// FETCH_SIZE 787MB = 2x compulsory, 3.3 TB/s, 245us.
// Now: the 32KB block = 2000 float4 flat; instr j: lane l reads f4 64j+l
// (contiguous 1024B, every sector fully consumed). Since 64 = 4 (mod 5),
// per-lane (row-offset, quad) is loop-invariant over groups of 5 instrs:
//   rj[j] = (64j+lane)/5,  qj[j] = (lane+4j) % 5
// Accumulate branch-free into 5 acc quads via cndmask selects (~25 VALU/load;
// VALUBusy was 2.4% -> ~10x headroom). W staged in LDS (gather spans only
// ~13 words -> near-broadcast). Block = 4 waves = {Q,K,V,cdd} of one pos ->
// uniform workload. Grid 4000 blocks. Butterfly reduce, lane 0 writes 80B.
// ---------------------------------------------------------------------------
__global__ __launch_bounds__(256) void proj_kernel(
    const float* __restrict__ Q,
    const float* __restrict__ K,
    const float* __restrict__ V,
    const float* __restrict__ cdd,
    const float* __restrict__ W,
    const float* __restrict__ bptr,
    const float* __restrict__ W1,
    const float* __restrict__ b1ptr,
    float* __restrict__ proj)   // [4][NPOS][20] : q,k,v,c
{
    __shared__ float sW[DI];
    __shared__ float sW1[DKk];
    for (int i = threadIdx.x; i < DI; i += 256) sW[i] = W[i];
    if (threadIdx.x < DKk) sW1[threadIdx.x] = W1[threadIdx.x];
    __syncthreads();

    const int tensor = threadIdx.x >> 6;   // wave = tensor (0:Q 1:K 2:V 3:cdd)
    const int lane   = threadIdx.x & 63;
    const int pos    = blockIdx.x;         // 0..3999

    // loop-invariant per-lane row/quad patterns for the 5-instr period
    int rj[5], qj[5];
    #pragma unroll
    for (int j = 0; j < 5; ++j) {
        rj[j] = (64 * j + lane) / 5;
        qj[j] = (lane + 4 * j) % 5;
    }

    float4 acc[5];
    #pragma unroll
    for (int q = 0; q < 5; ++q) acc[q] = float4{0.f, 0.f, 0.f, 0.f};

    // branch-free select-accumulate: adds wn*x into acc[qv] only
#define ACCUM(xv, wnv, qv)                                                   \
    {                                                                        \
        float w0_ = (qv == 0) ? (wnv) : 0.f;                                 \
        float w1_ = (qv == 1) ? (wnv) : 0.f;                                 \
        float w2_ = (qv == 2) ? (wnv) : 0.f;                                 \
        float w3_ = (qv == 3) ? (wnv) : 0.f;                                 \
        float w4_ = (qv == 4) ? (wnv) : 0.f;                                 \
        acc[0].x += w0_ * xv.x; acc[0].y += w0_ * xv.y;                      \
        acc[0].z += w0_ * xv.z; acc[0].w += w0_ * xv.w;                      \
        acc[1].x += w1_ * xv.x; acc[1].y += w1_ * xv.y;                      \
        acc[1].z += w1_ * xv.z; acc[1].w += w1_ * xv.w;                      \
        acc[2].x += w2_ * xv.x; acc[2].y += w2_ * xv.y;                      \
        acc[2].z += w2_ * xv.z; acc[2].w += w2_ * xv.w;                      \
        acc[3].x += w3_ * xv.x; acc[3].y += w3_ * xv.y;                      \
        acc[3].z += w3_ * xv.z; acc[3].w += w3_ * xv.w;                      \
        acc[4].x += w4_ * xv.x; acc[4].y += w4_ * xv.y;                      \
        acc[4].z += w4_ * xv.z; acc[4].w += w4_ * xv.w;                      \
    }

    if (tensor < 3) {
        const float4* src = reinterpret_cast<const float4*>(
            ((tensor == 0) ? Q : (tensor == 1) ? K : V) + (size_t)pos * (DI * DKk));

        // 6 full groups of 5 instrs: f = 320g + 64j + lane, rows 64g + rj[j]
        for (int g = 0; g < 6; ++g) {
            float4 x[5];
            #pragma unroll
            for (int j = 0; j < 5; ++j)
                x[j] = src[320 * g + 64 * j + lane];
            float wns[5];
            #pragma unroll
            for (int j = 0; j < 5; ++j)
                wns[j] = sW[64 * g + rj[j]];
            #pragma unroll
            for (int j = 0; j < 5; ++j)
                ACCUM(x[j], wns[j], qj[j]);
        }
        // tail group g=6: j=0 full (f 1920..1983), j=1 lanes<16 (f 1984..1999)
        {
            float4 x0 = src[320 * 6 + lane];
            float wn0 = sW[384 + rj[0]];
            ACCUM(x0, wn0, qj[0]);
            if (lane < 16) {
                float4 x1 = src[320 * 6 + 64 + lane];
                float wn1 = sW[384 + rj[1]];
                ACCUM(x1, wn1, qj[1]);
            }
        }
    } else {
        // cdd: 100 f4 = j=0 full + j=1 lanes<36; rows rj[j] (0..19), W1
        const float4* src = reinterpret_cast<const float4*>(
            cdd + (size_t)pos * (DKk * DKk));
        float4 x0 = src[lane];
        float wn0 = sW1[rj[0]];
        ACCUM(x0, wn0, qj[0]);
        if (lane < 36) {
            float4 x1 = src[64 + lane];
            float wn1 = sW1[rj[1]];
            ACCUM(x1, wn1, qj[1]);
        }
    }
#undef ACCUM

    // full-wave butterfly: every lane ends with the complete 20 sums
    #pragma unroll
    for (int m = 32; m >= 1; m >>= 1) {
        #pragma unroll
        for (int q = 0; q < 5; ++q) {
            acc[q].x += __shfl_xor(acc[q].x, m);
            acc[q].y += __shfl_xor(acc[q].y, m);
            acc[q].z += __shfl_xor(acc[q].z, m);
            acc[q].w += __shfl_xor(acc[q].w, m);
        }
    }

    if (lane == 0) {
        const float bias = (tensor < 3) ? bptr[0] : b1ptr[0];
        float4* dst = reinterpret_cast<float4*>(
            proj + ((size_t)tensor * NPOS + pos) * DKk);
        #pragma unroll
        for (int q = 0; q < 5; ++q) {
            float4 o;
            o.x = acc[q].x + bias;
            o.y = acc[q].y + bias;
            o.z = acc[q].z + bias;
            o.w = acc[q].w + bias;
            dst[q] = o;
        }
    }
}

// ---------------------------------------------------------------------------
// Kernel 2: attention + fused normalization. R7: one WAVE per output row
// (was 32 threads/row): 1000 blocks (20 bc x 50 tiles), 4 rows/block,
// width-64 reductions. Doubles parallelism (2000 -> 4000 waves); staging
// traffic 1000 x 48KB = 48MB from L2-resident proj (~1.4us) - negligible.
// Stride-80B LDS b128 reads are already bank-group conflict-optimal
// (80/16 = 5 is odd -> all 8 bank-groups hit per 8 lanes).
// ---------------------------------------------------------------------------
__global__ __launch_bounds__(256) void attn_kernel(
    const float* __restrict__ proj,
    float* __restrict__ attn_out,  // [NPOS][200] fp32, normalized (in d_out)
    float* __restrict__ ctx_out)   // [NPOS][20] fp32 (d_out head)
{
    __shared__ float sk[HH * DKk];
    __shared__ float sc[HH * DKk];
    __shared__ float sv[HH * DKk];

    int bc   = blockIdx.x / 50;
    int tile = blockIdx.x % 50;
    int t    = threadIdx.x;

    const float* kp = proj + ((size_t)1 * NPOS + bc * HH) * DKk;
    const float* vp = proj + ((size_t)2 * NPOS + bc * HH) * DKk;
    const float* cp = proj + ((size_t)3 * NPOS + bc * HH) * DKk;

    for (int i = t; i < HH * DKk / 4; i += 256) {
        reinterpret_cast<float4*>(sk)[i] = reinterpret_cast<const float4*>(kp)[i];
        reinterpret_cast<float4*>(sc)[i] = reinterpret_cast<const float4*>(cp)[i];
        reinterpret_cast<float4*>(sv)[i] = reinterpret_cast<const float4*>(vp)[i];
    }
    __syncthreads();

    int row = t >> 6;            // 0..3  (one wave per row)
    int sub = t & 63;            // 0..63
    int h   = tile * 4 + row;    // 0..199
    int rowIdx = bc * HH + h;

    const float* qr_p = proj + ((size_t)0 * NPOS + rowIdx) * DKk;
    const float* kr_p = proj + ((size_t)1 * NPOS + rowIdx) * DKk;
    float qr[DKk], kr[DKk];
    #pragma unroll
    for (int i = 0; i < 5; ++i) {
        float4 a = reinterpret_cast<const float4*>(qr_p)[i];
        qr[4*i] = a.x; qr[4*i+1] = a.y; qr[4*i+2] = a.z; qr[4*i+3] = a.w;
        float4 b = reinterpret_cast<const float4*>(kr_p)[i];
        kr[4*i] = b.x; kr[4*i+1] = b.y; kr[4*i+2] = b.z; kr[4*i+3] = b.w;
    }

    const float inv_sqrt = 0.22360679774997896f;  // 1/sqrt(20)
    float ctx[DKk];
    #pragma unroll
    for (int d = 0; d < DKk; ++d) ctx[d] = 0.f;
    float rs = 0.f;
    float sreg[4];   // s values in registers (static indexing via unroll)

    #pragma unroll
    for (int kk = 0; kk < 4; ++kk) {
        int g = sub + 64 * kk;
        float s = 0.f;
        if (g < HH) {
            float dot = 0.f;
            #pragma unroll
            for (int i = 0; i < 5; ++i) {
                float4 kg = reinterpret_cast<const float4*>(sk + g * DKk)[i];
                float4 cg = reinterpret_cast<const float4*>(sc + g * DKk)[i];
                dot += qr[4*i]   * kg.x + qr[4*i+1] * kg.y
                     + qr[4*i+2] * kg.z + qr[4*i+3] * kg.w;
                dot += kr[4*i]   * cg.x + kr[4*i+1] * cg.y
                     + kr[4*i+2] * cg.z + kr[4*i+3] * cg.w;
            }
            s = __expf(dot * inv_sqrt);
            #pragma unroll
            for (int i = 0; i < 5; ++i) {
                float4 vg = reinterpret_cast<const float4*>(sv + g * DKk)[i];
                ctx[4*i]   += s * vg.x;
                ctx[4*i+1] += s * vg.y;
                ctx[4*i+2] += s * vg.z;
                ctx[4*i+3] += s * vg.w;
            }
        }
        sreg[kk] = s;
        rs += s;
    }

    // width-64 butterflies: all lanes end with rowsum / full ctx
    #pragma unroll
    for (int off = 32; off >= 1; off >>= 1)
        rs += __shfl_xor(rs, off);
    float inv = 1.0f / (rs + 1e-8f);

    #pragma unroll
    for (int off = 32; off >= 1; off >>= 1) {
        #pragma unroll
        for (int d = 0; d < DKk; ++d)
            ctx[d] += __shfl_xor(ctx[d], off);
    }

    if (sub == 0) {
        float* co = ctx_out + (size_t)rowIdx * DKk;
        #pragma unroll
        for (int i = 0; i < 5; ++i) {
            float4 o;
            o.x = ctx[4*i]   * inv;
            o.y = ctx[4*i+1] * inv;
            o.z = ctx[4*i+2] * inv;
            o.w = ctx[4*i+3] * inv;
            reinterpret_cast<float4*>(co)[i] = o;
        }
    }

    // normalized attn straight from registers (coalesced 256B per wave)
    #pragma unroll
    for (int kk = 0; kk < 4; ++kk) {
        int g = sub + 64 * kk;
        if (g < HH)
            attn_out[(size_t)rowIdx * HH + g] = sreg[kk] * inv;
    }
}

extern "C" void kernel_launch(void* const* d_in, const int* in_sizes, int n_in,
                              void* d_out, int out_size, void* d_ws, size_t ws_size,
                              hipStream_t stream) {
    const float* Q   = (const float*)d_in[0];
    const float* K   = (const float*)d_in[1];
    const float* V   = (const float*)d_in[2];
    const float* cdd = (const float*)d_in[3];
    const float* W   = (const float*)d_in[4];
    const float* b   = (const float*)d_in[5];
    const float* W1  = (const float*)d_in[6];
    const float* b1  = (const float*)d_in[7];
    // d_in[8] = d_k (int) — compile-time constant 20

    float* proj = (float*)d_ws;           // 4*4000*20 = 320000 floats = 1.28 MB

    float* out      = (float*)d_out;
    float* ctx_out  = out;                // 80000 fp32 (context)
    float* attn_out = out + 80000;        // 800000 fp32 (attn)

    // one block per pos: 4 waves = {Q,K,V,cdd} of the same pos
    proj_kernel<<<NPOS, 256, 0, stream>>>(
        Q, K, V, cdd, W, b, W1, b1, proj);
    // one wave per output row: 20 bc * 50 tiles = 1000 blocks
    attn_kernel<<<CC * BB * 50, 256, 0, stream>>>(proj, attn_out, ctx_out);
}

// Round 4
// 373.503 us; speedup vs baseline: 1.3040x; 1.0068x over previous
//
#include <hip/hip_runtime.h>

#define BB 4
#define CC 5
#define HH 200
#define DKk 20
#define DI 400
#define NPOS (BB*CC*HH)   // 4000
#define TILE_F4 2000      // 400 rows x 20 floats = 2000 float4 = 32000 B
#define TILE_PAD 2048     // padded so clamped tail lanes land in-bounds

// async global->LDS, 16B per lane: lane l writes ldsbase + l*16 (linear).
__device__ __forceinline__ void load_to_lds16(const void* g, void* l) {
    __builtin_amdgcn_global_load_lds(
        (const __attribute__((address_space(1))) unsigned int*)g,
        (__attribute__((address_space(3))) unsigned int*)l, 16, 0, 0);
}

// branch-free select-accumulate: adds wn*x into acc[qv] only (R3-proven)
#define ACCUM(xv, wnv, qv)                                                   \
    {                                                                        \
        float w0_ = ((qv) == 0) ? (wnv) : 0.f;                               \
        float w1_ = ((qv) == 1) ? (wnv) : 0.f;                               \
        float w2_ = ((qv) == 2) ? (wnv) : 0.f;                               \
        float w3_ = ((qv) == 3) ? (wnv) : 0.f;                               \
        float w4_ = ((qv) == 4) ? (wnv) : 0.f;                               \
        acc[0].x += w0_ * (xv).x; acc[0].y += w0_ * (xv).y;                  \
        acc[0].z += w0_ * (xv).z; acc[0].w += w0_ * (xv).w;                  \
        acc[1].x += w1_ * (xv).x; acc[1].y += w1_ * (xv).y;                  \
        acc[1].z += w1_ * (xv).z; acc[1].w += w1_ * (xv).w;                  \
        acc[2].x += w2_ * (xv).x; acc[2].y += w2_ * (xv).y;                  \
        acc[2].z += w2_ * (xv).z; acc[2].w += w2_ * (xv).w;                  \
        acc[3].x += w3_ * (xv).x; acc[3].y += w3_ * (xv).y;                  \
        acc[3].z += w3_ * (xv).z; acc[3].w += w3_ * (xv).w;                  \
        acc[4].x += w4_ * (xv).x; acc[4].y += w4_ * (xv).y;                  \
        acc[4].z += w4_ * (xv).z; acc[4].w += w4_ * (xv).w;                  \
    }

// ---------------------------------------------------------------------------
// Kernel 1a: q/k/v projections via global_load_lds tile staging. R8.
// R7 lesson: 3 register-path structures all pin at ~390MB/140us = 2.8 TB/s
// with VALUBusy 10%: duty-cycled latency-bound (issue 5 -> drain vmcnt(0) ->
// compute 250cy). Fix per guide Common-mistake #1: stage the whole 32KB
// (tensor,pos) tile to LDS with 8 back-to-back global_load_lds (no VGPR
// writeback -> no per-load dependency; 32KB in flight per block, 4 blocks/CU
// = 128KB/CU sustained). Compute phase = R3's flat-f4 select-ACCUM, now from
// LDS (contiguous ds_read_b128). Wave butterfly + LDS cross-wave combine.
// Grid: 3*4000 = 12000 blocks x 256.
// ---------------------------------------------------------------------------
__global__ __launch_bounds__(256) void proj_qkv_kernel(
    const float* __restrict__ Q,
    const float* __restrict__ K,
    const float* __restrict__ V,
    const float* __restrict__ W,
    const float* __restrict__ bptr,
    float* __restrict__ proj)   // [4][NPOS][20] : q,k,v,c
{
    __shared__ float4 tile[TILE_PAD];   // 32768 B
    __shared__ float  sW[DI];           // 1600 B
    __shared__ float  red[4][DKk];      // 320 B

    const int t    = threadIdx.x;
    const int wave = t >> 6;
    const int lane = t & 63;
    const int tensor = blockIdx.x / NPOS;   // 0..2
    const int pos    = blockIdx.x % NPOS;

    const float* base = (tensor == 0) ? Q : (tensor == 1) ? K : V;
    const float4* gsrc = reinterpret_cast<const float4*>(
        base + (size_t)pos * (DI * DKk));

    for (int i = t; i < DI; i += 256) sW[i] = W[i];

    // stage 2000 f4 in 8 rounds; all 8 issued before any wait.
    // LDS dest must be wave-uniform base (+lane*16 implicit): tile + r*256 + wave*64.
    #pragma unroll
    for (int r = 0; r < 8; ++r) {
        int idx = r * 256 + t;
        int cidx = (idx < TILE_F4) ? idx : (TILE_F4 - 1);   // clamp tail (slots 2000..2047 get dup, never read)
        load_to_lds16((const void*)(gsrc + cidx),
                      (void*)(tile + r * 256 + wave * 64));
    }
    __syncthreads();   // compiler emits vmcnt(0)+lgkmcnt(0) drain here - wanted

    // compute: thread t owns flat f4 indices t+256r. row = f/5, quad = f%5.
    // 256 % 5 == 1  =>  quad for round r = (t%5 + r) % 5.
    float4 acc[5];
    #pragma unroll
    for (int q = 0; q < 5; ++q) acc[q] = float4{0.f, 0.f, 0.f, 0.f};
    const int q0 = t % 5;

    float4 xs[7];
    float  wns[7];
    #pragma unroll
    for (int r = 0; r < 7; ++r) xs[r] = tile[r * 256 + t];
    #pragma unroll
    for (int r = 0; r < 7; ++r) wns[r] = sW[(r * 256 + t) / 5];
    #pragma unroll
    for (int r = 0; r < 7; ++r) {
        int q = q0 + r; if (q >= 5) q -= 5; if (q >= 5) q -= 5;
        ACCUM(xs[r], wns[r], q);
    }
    if (t < TILE_F4 - 7 * 256) {     // tail round r=7: idx 1792..1999
        int idx = 7 * 256 + t;
        float4 x = tile[idx];
        float wn = sW[idx / 5];
        int q = q0 + 7; if (q >= 5) q -= 5; if (q >= 5) q -= 5;
        ACCUM(x, wn, q);
    }

    // wave butterfly: every lane gets the wave's 20 sums
    #pragma unroll
    for (int m = 32; m >= 1; m >>= 1) {
        #pragma unroll
        for (int q = 0; q < 5; ++q) {
            acc[q].x += __shfl_xor(acc[q].x, m);
            acc[q].y += __shfl_xor(acc[q].y, m);
            acc[q].z += __shfl_xor(acc[q].z, m);
            acc[q].w += __shfl_xor(acc[q].w, m);
        }
    }
    if (lane == 0) {
        #pragma unroll
        for (int q = 0; q < 5; ++q) {
            red[wave][4*q+0] = acc[q].x;
            red[wave][4*q+1] = acc[q].y;
            red[wave][4*q+2] = acc[q].z;
            red[wave][4*q+3] = acc[q].w;
        }
    }
    __syncthreads();
    if (t < DKk) {
        float s = red[0][t] + red[1][t] + red[2][t] + red[3][t] + bptr[0];
        proj[((size_t)tensor * NPOS + pos) * DKk + t] = s;
    }
}

// ---------------------------------------------------------------------------
// Kernel 1b: cdd projection (1.6% of traffic). R3-proven wave-direct path.
// One wave per pos: 1000 blocks x 4 waves.
// ---------------------------------------------------------------------------
__global__ __launch_bounds__(256) void proj_cdd_kernel(
    const float* __restrict__ cdd,
    const float* __restrict__ W1,
    const float* __restrict__ b1ptr,
    float* __restrict__ proj)
{
    const int wave = threadIdx.x >> 6;
    const int lane = threadIdx.x & 63;
    const int pos  = blockIdx.x * 4 + wave;   // 0..3999, exact

    int rj0 = lane / 5,        qj0 = lane % 5;
    int rj1 = (64 + lane) / 5, qj1 = (lane + 4) % 5;

    float4 acc[5];
    #pragma unroll
    for (int q = 0; q < 5; ++q) acc[q] = float4{0.f, 0.f, 0.f, 0.f};

    const float4* src = reinterpret_cast<const float4*>(
        cdd + (size_t)pos * (DKk * DKk));
    {
        float4 x0 = src[lane];
        float wn0 = W1[rj0];
        ACCUM(x0, wn0, qj0);
    }
    if (lane < 36) {
        float4 x1 = src[64 + lane];
        float wn1 = W1[rj1];
        ACCUM(x1, wn1, qj1);
    }

    #pragma unroll
    for (int m = 32; m >= 1; m >>= 1) {
        #pragma unroll
        for (int q = 0; q < 5; ++q) {
            acc[q].x += __shfl_xor(acc[q].x, m);
            acc[q].y += __shfl_xor(acc[q].y, m);
            acc[q].z += __shfl_xor(acc[q].z, m);
            acc[q].w += __shfl_xor(acc[q].w, m);
        }
    }
    if (lane == 0) {
        const float bias = b1ptr[0];
        float4* dst = reinterpret_cast<float4*>(
            proj + ((size_t)3 * NPOS + pos) * DKk);
        #pragma unroll
        for (int q = 0; q < 5; ++q) {
            float4 o;
            o.x = acc[q].x + bias;
            o.y = acc[q].y + bias;
            o.z = acc[q].z + bias;
            o.w = acc[q].w + bias;
            dst[q] = o;
        }
    }
}

// ---------------------------------------------------------------------------
// Kernel 2: attention + fused normalization (unchanged from R7; ~10us,
// invisible in top-5). One wave per output row; width-64 butterflies.
// ---------------------------------------------------------------------------
__global__ __launch_bounds__(256) void attn_kernel(
    const float* __restrict__ proj,
    float* __restrict__ attn_out,  // [NPOS][200] fp32, normalized (in d_out)
    float* __restrict__ ctx_out)   // [NPOS][20] fp32 (d_out head)
{
    __shared__ float sk[HH * DKk];
    __shared__ float sc[HH * DKk];
    __shared__ float sv[HH * DKk];

    int bc   = blockIdx.x / 50;
    int tile = blockIdx.x % 50;
    int t    = threadIdx.x;

    const float* kp = proj + ((size_t)1 * NPOS + bc * HH) * DKk;
    const float* vp = proj + ((size_t)2 * NPOS + bc * HH) * DKk;
    const float* cp = proj + ((size_t)3 * NPOS + bc * HH) * DKk;

    for (int i = t; i < HH * DKk / 4; i += 256) {
        reinterpret_cast<float4*>(sk)[i] = reinterpret_cast<const float4*>(kp)[i];
        reinterpret_cast<float4*>(sc)[i] = reinterpret_cast<const float4*>(cp)[i];
        reinterpret_cast<float4*>(sv)[i] = reinterpret_cast<const float4*>(vp)[i];
    }
    __syncthreads();

    int row = t >> 6;            // 0..3  (one wave per row)
    int sub = t & 63;            // 0..63
    int h   = tile * 4 + row;    // 0..199
    int rowIdx = bc * HH + h;

    const float* qr_p = proj + ((size_t)0 * NPOS + rowIdx) * DKk;
    const float* kr_p = proj + ((size_t)1 * NPOS + rowIdx) * DKk;
    float qr[DKk], kr[DKk];
    #pragma unroll
    for (int i = 0; i < 5; ++i) {
        float4 a = reinterpret_cast<const float4*>(qr_p)[i];
        qr[4*i] = a.x; qr[4*i+1] = a.y; qr[4*i+2] = a.z; qr[4*i+3] = a.w;
        float4 b = reinterpret_cast<const float4*>(kr_p)[i];
        kr[4*i] = b.x; kr[4*i+1] = b.y; kr[4*i+2] = b.z; kr[4*i+3] = b.w;
    }

    const float inv_sqrt = 0.22360679774997896f;  // 1/sqrt(20)
    float ctx[DKk];
    #pragma unroll
    for (int d = 0; d < DKk; ++d) ctx[d] = 0.f;
    float rs = 0.f;
    float sreg[4];

    #pragma unroll
    for (int kk = 0; kk < 4; ++kk) {
        int g = sub + 64 * kk;
        float s = 0.f;
        if (g < HH) {
            float dot = 0.f;
            #pragma unroll
            for (int i = 0; i < 5; ++i) {
                float4 kg = reinterpret_cast<const float4*>(sk + g * DKk)[i];
                float4 cg = reinterpret_cast<const float4*>(sc + g * DKk)[i];
                dot += qr[4*i]   * kg.x + qr[4*i+1] * kg.y
                     + qr[4*i+2] * kg.z + qr[4*i+3] * kg.w;
                dot += kr[4*i]   * cg.x + kr[4*i+1] * cg.y
                     + kr[4*i+2] * cg.z + kr[4*i+3] * cg.w;
            }
            s = __expf(dot * inv_sqrt);
            #pragma unroll
            for (int i = 0; i < 5; ++i) {
                float4 vg = reinterpret_cast<const float4*>(sv + g * DKk)[i];
                ctx[4*i]   += s * vg.x;
                ctx[4*i+1] += s * vg.y;
                ctx[4*i+2] += s * vg.z;
                ctx[4*i+3] += s * vg.w;
            }
        }
        sreg[kk] = s;
        rs += s;
    }

    #pragma unroll
    for (int off = 32; off >= 1; off >>= 1)
        rs += __shfl_xor(rs, off);
    float inv = 1.0f / (rs + 1e-8f);

    #pragma unroll
    for (int off = 32; off >= 1; off >>= 1) {
        #pragma unroll
        for (int d = 0; d < DKk; ++d)
            ctx[d] += __shfl_xor(ctx[d], off);
    }

    if (sub == 0) {
        float* co = ctx_out + (size_t)rowIdx * DKk;
        #pragma unroll
        for (int i = 0; i < 5; ++i) {
            float4 o;
            o.x = ctx[4*i]   * inv;
            o.y = ctx[4*i+1] * inv;
            o.z = ctx[4*i+2] * inv;
            o.w = ctx[4*i+3] * inv;
            reinterpret_cast<float4*>(co)[i] = o;
        }
    }

    #pragma unroll
    for (int kk = 0; kk < 4; ++kk) {
        int g = sub + 64 * kk;
        if (g < HH)
            attn_out[(size_t)rowIdx * HH + g] = sreg[kk] * inv;
    }
}

extern "C" void kernel_launch(void* const* d_in, const int* in_sizes, int n_in,
                              void* d_out, int out_size, void* d_ws, size_t ws_size,
                              hipStream_t stream) {
    const float* Q   = (const float*)d_in[0];
    const float* K   = (const float*)d_in[1];
    const float* V   = (const float*)d_in[2];
    const float* cdd = (const float*)d_in[3];
    const float* W   = (const float*)d_in[4];
    const float* b   = (const float*)d_in[5];
    const float* W1  = (const float*)d_in[6];
    const float* b1  = (const float*)d_in[7];
    // d_in[8] = d_k (int) — compile-time constant 20

    float* proj = (float*)d_ws;           // 4*4000*20 = 320000 floats = 1.28 MB

    float* out      = (float*)d_out;
    float* ctx_out  = out;                // 80000 fp32 (context)
    float* attn_out = out + 80000;        // 800000 fp32 (attn)

    proj_qkv_kernel<<<3 * NPOS, 256, 0, stream>>>(Q, K, V, W, b, proj);
    proj_cdd_kernel<<<NPOS / 4, 256, 0, stream>>>(cdd, W1, b1, proj);
    attn_kernel<<<CC * BB * 50, 256, 0, stream>>>(proj, attn_out, ctx_out);
}